// Round 9
// baseline (188.615 us; speedup 1.0000x reference)
//
#include <hip/hip_runtime.h>
#include <hip/hip_fp16.h>

#define SCALE_F 10000.0f
#define PSF 21
#define PAD 10
#define PSF3 9261        // 21*21*21 packed
#define ROWP 22          // padded x-row length (halfs)
#define ZSTR 462         // 21*22, halfs per z-plane (even)
#define PSFP 9704        // padded psf stride in halfs (441*22=9702 -> 9704 for 8B align)
#define NQUAD 2426       // 9704/4 ushort4 quads
#define NTILES 16384     // 16 channels * 32 * 32
#define CAP 64

typedef float f32x4 __attribute__((ext_vector_type(4)));
typedef float f32x2 __attribute__((ext_vector_type(2)));

// workspace layout (bytes)
#define META_OFF 0                 // 8192*16 = 131072
#define CNT_OFF  131072            // 16384*4 = 65536
#define SCAN_OFF 196608            // 16384*4 (fp32 fallback)
#define CUR_OFF  262144            // 16384*4 (fp32 fallback)
#define LIST_OFF 327680            // cap list (CAP*16384*4 = 4 MB) or exact list
#define PSC_OFF  4521984           // 256-aligned; + 8192*PSFP*2 B

// ============ primary: fused scale + fp16-padded materialize + bin/fill ============
// Phase A: packed float4 read into regs, block max-reduce -> sc.
// Phase A2: convert to fp16, stage packed into LDS.
// Phase B: write padded layout: row r at r*22, data shifted by s=x0&1, pad zeroed.
__global__ __launch_bounds__(256) void psf_scale_fill_f16(
    const float* __restrict__ psf_raw,
    const float* __restrict__ i_val,
    const int* __restrict__ bArr, const int* __restrict__ chArr,
    const int* __restrict__ zArr, const int* __restrict__ yArr,
    const int* __restrict__ xArr,
    int4* __restrict__ meta,
    int*  __restrict__ cnt,
    int*  __restrict__ list,
    __half* __restrict__ pscaled)
{
    const int n   = blockIdx.x;
    const int tid = threadIdx.x;
    const float* p = psf_raw + (size_t)n * PSF3;

    const int peel = (4 - (n & 3)) & 3;        // elems until 16B alignment
    const f32x4* p4 = (const f32x4*)(p + peel);
    const int nq  = (PSF3 - peel) >> 2;
    const int rem = (PSF3 - peel) & 3;

    float head = 0.0f, tailv = 0.0f;
    if (tid < peel) head  = p[tid];
    if (tid < rem)  tailv = p[PSF3 - rem + tid];

    f32x4 q[10];
    float m = fmaxf(fmaxf(head, tailv), 0.0f);
#pragma unroll
    for (int j = 0; j < 10; ++j) {
        const int k = tid + (j << 8);
        if (j < 9 || k < nq) {
            f32x4 v = __builtin_nontemporal_load(p4 + k);
            q[j] = v;
            m = fmaxf(m, fmaxf(fmaxf(v.x, v.y), fmaxf(v.z, v.w)));
        } else {
            q[j] = (f32x4)(0.0f);
        }
    }

#pragma unroll
    for (int off = 32; off > 0; off >>= 1)
        m = fmaxf(m, __shfl_down(m, off, 64));

    __shared__ float smax[4];
    __shared__ unsigned short lds[PSF3];       // packed fp16 staging (18522 B)
    if ((tid & 63) == 0) smax[tid >> 6] = m;
    __syncthreads();
    const float mm = fmaxf(fmaxf(smax[0], smax[1]), fmaxf(smax[2], smax[3]));
    const float sc = (mm > 0.0f) ? SCALE_F * fmaxf(i_val[n], 0.0f) / mm : 0.0f;

    // Phase A2: stage packed fp16 into LDS
    if (tid < peel)
        lds[tid] = __half_as_ushort(__float2half_rn(sc * fmaxf(head, 0.0f)));
    if (tid < rem)
        lds[PSF3 - rem + tid] = __half_as_ushort(__float2half_rn(sc * fmaxf(tailv, 0.0f)));
#pragma unroll
    for (int j = 0; j < 10; ++j) {
        const int k = tid + (j << 8);
        if (j < 9 || k < nq) {
            const int base = peel + (k << 2);
            lds[base + 0] = __half_as_ushort(__float2half_rn(sc * fmaxf(q[j].x, 0.0f)));
            lds[base + 1] = __half_as_ushort(__float2half_rn(sc * fmaxf(q[j].y, 0.0f)));
            lds[base + 2] = __half_as_ushort(__float2half_rn(sc * fmaxf(q[j].z, 0.0f)));
            lds[base + 3] = __half_as_ushort(__float2half_rn(sc * fmaxf(q[j].w, 0.0f)));
        }
    }
    __syncthreads();

    // Phase B: padded store. position j in row holds psf x = j - s (s = x0&1), else 0.
    const int x0 = xArr[n] - PAD;
    const int s  = x0 & 1;
    ushort4* outp = (ushort4*)(pscaled + (size_t)n * PSFP);
#pragma unroll
    for (int it = 0; it < 10; ++it) {
        const int q4 = tid + (it << 8);
        if (it < 9 || q4 < NQUAD) {
            const int o0 = q4 << 2;
            ushort4 u;
#pragma unroll
            for (int cc = 0; cc < 4; ++cc) {
                const int o   = o0 + cc;
                const int row = o / ROWP;          // magic-mul
                const int j   = o - row * ROWP;
                const int px  = j - s;
                unsigned short val = 0;
                if ((unsigned)px < 21u && row < 441)
                    val = lds[row * 21 + px];
                (&u.x)[cc] = val;
            }
            outp[q4] = u;
        }
    }

    if (tid == 0) {
        int z0 = zArr[n] - PAD, y0 = yArr[n] - PAD;
        meta[n] = make_int4(z0, y0, x0, __float_as_int(sc));
        int c = bArr[n] * 16 + chArr[n];
        int tzlo = max(z0, 0) >> 3, tzhi = min(z0 + 20, 255) >> 3;
        int tylo = max(y0, 0) >> 3, tyhi = min(y0 + 20, 255) >> 3;
        for (int tz = tzlo; tz <= tzhi; ++tz)
            for (int ty = tylo; ty <= tyhi; ++ty) {
                int t = c * 1024 + tz * 32 + ty;
                int pos = atomicAdd(&cnt[t], 1);
                if (pos < CAP) list[t * CAP + pos] = n;
            }
    }
}

// ============ primary gather: thread = (x-pair 0..31) x (y-row 0..7) ============
// One half2 load per thread per z covers 2 output x; wave covers 2 y-rows.
__global__ __launch_bounds__(256) void gather_f16(
    const __half* __restrict__ pscaled,
    const int4* __restrict__ meta,
    const int* __restrict__ cnt,
    const int* __restrict__ list,
    float* __restrict__ out)
{
    const int b  = blockIdx.x;
    const int ty = b & 31;
    const int tz = (b >> 5) & 31;
    const int c  = b >> 10;
    const int tile = b;

    const int t    = threadIdx.x;
    const int xp   = t & 31;          // x-pair index: covers x = 2xp, 2xp+1
    const int yrow = t >> 5;          // 0..7
    const int zbase = tz * 8;
    const int ybase = ty * 8;

    float acc0[8] = {};
    float acc1[8] = {};

    const int o  = tile * CAP;
    const int cn = min(cnt[tile], CAP);

    int  nnext = (cn > 0) ? list[o] : 0;
    int4 mnext = (cn > 0) ? meta[nnext] : make_int4(0, 0, 0, 0);

    for (int i = 0; i < cn; ++i) {
        const int  n  = __builtin_amdgcn_readfirstlane(nnext);
        const int4 mt = mnext;
        const int  nj = list[o + min(i + 1, cn - 1)];
        nnext = nj;
        mnext = meta[nj];

        const int z0 = __builtin_amdgcn_readfirstlane(mt.x);
        const int y0 = __builtin_amdgcn_readfirstlane(mt.y);
        const int x0 = __builtin_amdgcn_readfirstlane(mt.z);
        const int x0e = x0 & ~1;

        const int dy = ybase + yrow - y0;
        if (!__any((unsigned)dy < 21u)) continue;   // both wave rows miss

        const int dxs = 2 * xp - x0e;               // even
        const bool wy  = (unsigned)dy < 21u;
        const float wxy0 = (wy && (unsigned)dxs       < 22u) ? 1.0f : 0.0f;
        const float wxy1 = (wy && (unsigned)(dxs + 1) < 22u) ? 1.0f : 0.0f;

        const int dxsc = min(max(dxs, 0), 20);      // even, in-bounds base
        const int rowoff = min(max(dy, 0), 20) * ROWP + dxsc;
        const __half* pb = pscaled + (size_t)n * PSFP;

#pragma unroll
        for (int zi = 0; zi < 8; ++zi) {
            const int dz = zbase + zi - z0;          // scalar
            const int zo = min(max(dz, 0), 20) * ZSTR;
            const bool okz = (unsigned)dz < 21u;
            const __half2 hv = *reinterpret_cast<const __half2*>(pb + zo + rowoff);
            const float2 f = __half22float2(hv);
            const float w0 = okz ? wxy0 : 0.0f;
            const float w1 = okz ? wxy1 : 0.0f;
            acc0[zi] += w0 * f.x;
            acc1[zi] += w1 * f.y;
        }
    }

    // nt write-out: float2 per z-row
    const size_t outbase = (((size_t)c * 256 + zbase) * 256 + ybase + yrow) * 64 + 2 * xp;
#pragma unroll
    for (int zi = 0; zi < 8; ++zi) {
        f32x2 v; v.x = acc0[zi]; v.y = acc1[zi];
        __builtin_nontemporal_store(v,
            (f32x2*)(out + outbase + (size_t)zi * (256 * 64)));
    }
}

// ============ fp32 fallback path (small ws) ============
__global__ __launch_bounds__(256) void psf_scale_fill_f32(
    const float* __restrict__ psf_raw,
    const float* __restrict__ i_val,
    const int* __restrict__ bArr, const int* __restrict__ chArr,
    const int* __restrict__ zArr, const int* __restrict__ yArr,
    const int* __restrict__ xArr,
    int4* __restrict__ meta,
    int*  __restrict__ cnt,
    int*  __restrict__ list,
    int cap)
{
    const int n   = blockIdx.x;
    const int tid = threadIdx.x;
    const float* p = psf_raw + (size_t)n * PSF3;
    float m = 0.0f;
    for (int k = tid; k < PSF3; k += 256) m = fmaxf(m, p[k]);
#pragma unroll
    for (int off = 32; off > 0; off >>= 1)
        m = fmaxf(m, __shfl_down(m, off, 64));
    __shared__ float smax[4];
    if ((tid & 63) == 0) smax[tid >> 6] = m;
    __syncthreads();
    if (tid == 0) {
        float mm = fmaxf(fmaxf(smax[0], smax[1]), fmaxf(smax[2], smax[3]));
        float sc = (mm > 0.0f) ? SCALE_F * fmaxf(i_val[n], 0.0f) / mm : 0.0f;
        int z0 = zArr[n] - PAD, y0 = yArr[n] - PAD, x0 = xArr[n] - PAD;
        meta[n] = make_int4(z0, y0, x0, __float_as_int(sc));
        int c = bArr[n] * 16 + chArr[n];
        int tzlo = max(z0, 0) >> 3, tzhi = min(z0 + 20, 255) >> 3;
        int tylo = max(y0, 0) >> 3, tyhi = min(y0 + 20, 255) >> 3;
        for (int tz = tzlo; tz <= tzhi; ++tz)
            for (int ty = tylo; ty <= tyhi; ++ty) {
                int t = c * 1024 + tz * 32 + ty;
                if (cap > 0) {
                    int pos = atomicAdd(&cnt[t], 1);
                    if (pos < cap) list[t * cap + pos] = n;
                } else {
                    atomicAdd(&cnt[t], 1);
                }
            }
    }
}

__global__ __launch_bounds__(256) void scan_kernel(
    const int4* __restrict__ cnt4, int4* __restrict__ off4, int4* __restrict__ cur4)
{
    const int t = threadIdx.x;
    int4 v[16];
#pragma unroll
    for (int i = 0; i < 16; ++i) v[i] = cnt4[t * 16 + i];
    int sum = 0;
#pragma unroll
    for (int i = 0; i < 16; ++i) sum += v[i].x + v[i].y + v[i].z + v[i].w;
    const int lane = t & 63, w = t >> 6;
    int s = sum;
#pragma unroll
    for (int d = 1; d < 64; d <<= 1) {
        int u = __shfl_up(s, d, 64);
        if (lane >= d) s += u;
    }
    __shared__ int wsum[4];
    if (lane == 63) wsum[w] = s;
    __syncthreads();
    int base = 0;
    for (int i = 0; i < w; ++i) base += wsum[i];
    int run = base + s - sum;
#pragma unroll
    for (int i = 0; i < 16; ++i) {
        int4 oo;
        oo.x = run; run += v[i].x;
        oo.y = run; run += v[i].y;
        oo.z = run; run += v[i].z;
        oo.w = run; run += v[i].w;
        off4[t * 16 + i] = oo;
        cur4[t * 16 + i] = oo;
    }
}

__global__ __launch_bounds__(256) void fill_kernel(
    const int* __restrict__ bArr, const int* __restrict__ chArr,
    const int* __restrict__ zArr, const int* __restrict__ yArr,
    int* __restrict__ cursor, int* __restrict__ list, int N)
{
    int n = blockIdx.x * 256 + threadIdx.x;
    if (n >= N) return;
    int c = bArr[n] * 16 + chArr[n];
    int z0 = zArr[n] - PAD, y0 = yArr[n] - PAD;
    int tzlo = max(z0, 0) >> 3, tzhi = min(z0 + 20, 255) >> 3;
    int tylo = max(y0, 0) >> 3, tyhi = min(y0 + 20, 255) >> 3;
    for (int tz = tzlo; tz <= tzhi; ++tz)
        for (int ty = tylo; ty <= tyhi; ++ty) {
            int pos = atomicAdd(&cursor[c * 1024 + tz * 32 + ty], 1);
            list[pos] = n;
        }
}

__global__ __launch_bounds__(256) void gather_f32(
    const float* __restrict__ psf_raw,
    const int4* __restrict__ meta,
    const int* __restrict__ off, const int* __restrict__ cnt,
    const int* __restrict__ list,
    float* __restrict__ out,
    int cap)
{
    const int tile = blockIdx.x;
    const int ty = tile & 31;
    const int tz = (tile >> 5) & 31;
    const int c  = tile >> 10;
    const int t  = threadIdx.x;
    const int x    = t & 63;
    const int ysub = t >> 6;
    const int zbase = tz * 8;
    const int ybase = ty * 8;

    float acc0[8] = {};
    float acc1[8] = {};

    int o, cn;
    if (cap > 0) { o = tile * cap; cn = min(cnt[tile], cap); }
    else         { o = off[tile];  cn = cnt[tile]; }

    int  nnext = (cn > 0) ? list[o] : 0;
    int4 mnext = (cn > 0) ? meta[nnext] : make_int4(0, 0, 0, 0);

    for (int i = 0; i < cn; ++i) {
        const int  n  = __builtin_amdgcn_readfirstlane(nnext);
        const int4 mt = mnext;
        const int  nj = list[o + min(i + 1, cn - 1)];
        nnext = nj;
        mnext = meta[nj];

        const int z0 = __builtin_amdgcn_readfirstlane(mt.x);
        const int y0 = __builtin_amdgcn_readfirstlane(mt.y);
        const int x0 = __builtin_amdgcn_readfirstlane(mt.z);
        const float sc = __int_as_float(__builtin_amdgcn_readfirstlane(mt.w));

        const int dx  = x - x0;
        const float wsc = ((unsigned)dx < 21u) ? sc : 0.0f;
        const int dxc = min(max(dx, 0), 20);

        const int dy0 = ybase + ysub - y0;
        const int dy1 = dy0 + 4;
        const int a0 = __any((unsigned)dy0 < 21u);
        const int a1 = __any((unsigned)dy1 < 21u);
        const int row0 = min(max(dy0, 0), 20) * 21 + dxc;
        const int row1 = min(max(dy1, 0), 20) * 21 + dxc;
        const float* pb = psf_raw + (size_t)n * PSF3;

        if (a0 & a1) {
#pragma unroll
            for (int zi = 0; zi < 8; ++zi) {
                const int dz = zbase + zi - z0;
                const int zo = min(max(dz, 0), 20) * 441;
                const float w = ((unsigned)dz < 21u) ? wsc : 0.0f;
                acc0[zi] += w * fmaxf(pb[zo + row0], 0.0f);
                acc1[zi] += w * fmaxf(pb[zo + row1], 0.0f);
            }
        } else if (a0) {
#pragma unroll
            for (int zi = 0; zi < 8; ++zi) {
                const int dz = zbase + zi - z0;
                const int zo = min(max(dz, 0), 20) * 441;
                const float w = ((unsigned)dz < 21u) ? wsc : 0.0f;
                acc0[zi] += w * fmaxf(pb[zo + row0], 0.0f);
            }
        } else if (a1) {
#pragma unroll
            for (int zi = 0; zi < 8; ++zi) {
                const int dz = zbase + zi - z0;
                const int zo = min(max(dz, 0), 20) * 441;
                const float w = ((unsigned)dz < 21u) ? wsc : 0.0f;
                acc1[zi] += w * fmaxf(pb[zo + row1], 0.0f);
            }
        }
    }

    const size_t outbase = (((size_t)c * 256 + zbase) * 256 + ybase) * 64 + x;
#pragma unroll
    for (int zi = 0; zi < 8; ++zi) {
        __builtin_nontemporal_store(acc0[zi],
            &out[outbase + (size_t)zi * (256 * 64) + (size_t)ysub * 64]);
        __builtin_nontemporal_store(acc1[zi],
            &out[outbase + (size_t)zi * (256 * 64) + (size_t)(ysub + 4) * 64]);
    }
}

extern "C" void kernel_launch(void* const* d_in, const int* in_sizes, int n_in,
                              void* d_out, int out_size, void* d_ws, size_t ws_size,
                              hipStream_t stream) {
    const float* psf_raw = (const float*)d_in[0];
    const float* i_val   = (const float*)d_in[1];
    const int*   bArr    = (const int*)d_in[2];
    const int*   chArr   = (const int*)d_in[3];
    const int*   zArr    = (const int*)d_in[4];
    const int*   yArr    = (const int*)d_in[5];
    const int*   xArr    = (const int*)d_in[6];
    float* out = (float*)d_out;

    const int N = in_sizes[1];   // 8192 points

    char* ws = (char*)d_ws;
    int4*   meta    = (int4*)(ws + META_OFF);
    int*    cnt     = (int*)(ws + CNT_OFF);
    int*    offp    = (int*)(ws + SCAN_OFF);
    int*    cursor  = (int*)(ws + CUR_OFF);
    int*    list    = (int*)(ws + LIST_OFF);
    __half* pscaled = (__half*)(ws + PSC_OFF);

    const size_t f16_need = (size_t)PSC_OFF + (size_t)N * PSFP * 2;
    const bool f16 = (ws_size >= f16_need);

    (void)hipMemsetAsync(cnt, 0, NTILES * sizeof(int), stream);

    if (f16) {
        psf_scale_fill_f16<<<N, 256, 0, stream>>>(psf_raw, i_val, bArr, chArr,
            zArr, yArr, xArr, meta, cnt, list, pscaled);
        gather_f16<<<NTILES, 256, 0, stream>>>(pscaled, meta, cnt, list, out);
    } else {
        int cap;
        if (ws_size >= (size_t)LIST_OFF + (size_t)CAP * NTILES * 4) {
            cap = CAP;
        } else {
            size_t avail = (ws_size > LIST_OFF) ? ws_size - LIST_OFF : 0;
            size_t cap_s = avail / ((size_t)NTILES * sizeof(int));
            cap = (cap_s >= 24) ? (int)((cap_s < 64) ? cap_s : 64) : 0;
        }
        psf_scale_fill_f32<<<N, 256, 0, stream>>>(psf_raw, i_val, bArr, chArr,
            zArr, yArr, xArr, meta, cnt, list, cap);
        if (cap == 0) {
            scan_kernel<<<1, 256, 0, stream>>>((const int4*)cnt, (int4*)offp, (int4*)cursor);
            fill_kernel<<<(N + 255) / 256, 256, 0, stream>>>(bArr, chArr, zArr, yArr,
                                                             cursor, list, N);
        }
        gather_f32<<<NTILES, 256, 0, stream>>>(psf_raw, meta, offp, cnt, list, out, cap);
    }
}

// Round 10
// 167.986 us; speedup vs baseline: 1.1228x; 1.1228x over previous
//
#include <hip/hip_runtime.h>
#include <hip/hip_fp16.h>

#define SCALE_F 10000.0f
#define PSF 21
#define PAD 10
#define PSF3 9261        // 21*21*21
#define PSF3P 9280       // padded fp16 stride (even; 9280*2B = 290 cache lines)
#define NTILES 16384     // 16 channels * 32 * 32
#define CAP 64

typedef float f32x4 __attribute__((ext_vector_type(4)));

// workspace layout (bytes)
#define META_OFF 0                 // 8192*16 = 131072
#define CNT_OFF  131072            // 16384*4 = 65536
#define SCAN_OFF 196608            // 16384*4 (fallback)
#define CUR_OFF  262144            // 16384*4 (fallback)
#define LIST_OFF 327680            // cap list (CAP*16384*4 = 4 MB) or exact list
#define PSC_OFF  4521984           // 256-aligned; + 32B slack + 8192*9280*2 B

// ---------------- fused scale (+fp16 materialize) + bin/fill ----------------
template<bool F16>
__global__ __launch_bounds__(256) void psf_scale_fill_kernel(
    const float* __restrict__ psf_raw,
    const float* __restrict__ i_val,
    const int* __restrict__ bArr, const int* __restrict__ chArr,
    const int* __restrict__ zArr, const int* __restrict__ yArr,
    const int* __restrict__ xArr,
    int4* __restrict__ meta,
    int*  __restrict__ cnt,
    int*  __restrict__ list,
    int cap,
    __half* __restrict__ pscaled)   // base (+16 halfs slack applied by host)
{
    const int n   = blockIdx.x;
    const int tid = threadIdx.x;
    const float* p = psf_raw + (size_t)n * PSF3;

    const int peel = (4 - (n & 3)) & 3;        // elems until 16B alignment
    const f32x4* p4 = (const f32x4*)(p + peel);
    const int nq  = (PSF3 - peel) >> 2;        // 2314 or 2315 quads
    const int rem = (PSF3 - peel) & 3;

    float head = 0.0f, tailv = 0.0f;
    if (tid < peel) head  = p[tid];
    if (tid < rem)  tailv = p[PSF3 - rem + tid];

    f32x4 q[10];
    float m = fmaxf(fmaxf(head, tailv), 0.0f);
#pragma unroll
    for (int j = 0; j < 10; ++j) {
        const int k = tid + (j << 8);
        if (j < 9 || k < nq) {                 // j<9 always in range
            f32x4 v = __builtin_nontemporal_load(p4 + k);
            q[j] = v;
            m = fmaxf(m, fmaxf(fmaxf(v.x, v.y), fmaxf(v.z, v.w)));
        } else {
            q[j] = (f32x4)(0.0f);
        }
    }

#pragma unroll
    for (int off = 32; off > 0; off >>= 1)
        m = fmaxf(m, __shfl_down(m, off, 64));

    __shared__ float smax[4];
    if ((tid & 63) == 0) smax[tid >> 6] = m;
    __syncthreads();
    const float mm = fmaxf(fmaxf(smax[0], smax[1]), fmaxf(smax[2], smax[3]));
    const float sc = (mm > 0.0f) ? SCALE_F * fmaxf(i_val[n], 0.0f) / mm : 0.0f;

    if (F16) {
        // store pre-scaled, pre-ReLU fp16 at position idx-peel (8B-aligned quads)
        __half* pb = pscaled + (size_t)n * PSF3P;
        if (tid < peel)
            pb[tid - peel] = __float2half_rn(sc * fmaxf(head, 0.0f));
        if (tid < rem)
            pb[PSF3 - rem + tid - peel] = __float2half_rn(sc * fmaxf(tailv, 0.0f));
        ushort4* pq = (ushort4*)pb;            // n*PSF3P divisible by 4
#pragma unroll
        for (int j = 0; j < 10; ++j) {
            const int k = tid + (j << 8);
            if (j < 9 || k < nq) {
                ushort4 u;
                u.x = __half_as_ushort(__float2half_rn(sc * fmaxf(q[j].x, 0.0f)));
                u.y = __half_as_ushort(__float2half_rn(sc * fmaxf(q[j].y, 0.0f)));
                u.z = __half_as_ushort(__float2half_rn(sc * fmaxf(q[j].z, 0.0f)));
                u.w = __half_as_ushort(__float2half_rn(sc * fmaxf(q[j].w, 0.0f)));
                pq[k] = u;
            }
        }
    }

    if (tid == 0) {
        int z0 = zArr[n] - PAD, y0 = yArr[n] - PAD, x0 = xArr[n] - PAD;
        meta[n] = make_int4(z0, y0, x0, __float_as_int(sc));
        int c = bArr[n] * 16 + chArr[n];
        int tzlo = max(z0, 0) >> 3, tzhi = min(z0 + 20, 255) >> 3;
        int tylo = max(y0, 0) >> 3, tyhi = min(y0 + 20, 255) >> 3;
        if (cap > 0) {
            for (int tz = tzlo; tz <= tzhi; ++tz)
                for (int ty = tylo; ty <= tyhi; ++ty) {
                    int t = c * 1024 + tz * 32 + ty;
                    int pos = atomicAdd(&cnt[t], 1);
                    if (pos < cap) list[t * cap + pos] = n;
                }
        } else {
            for (int tz = tzlo; tz <= tzhi; ++tz)
                for (int ty = tylo; ty <= tyhi; ++ty)
                    atomicAdd(&cnt[c * 1024 + tz * 32 + ty], 1);
        }
    }
}

// ---------------- fallback: register-resident exclusive scan ----------------
__global__ __launch_bounds__(256) void scan_kernel(
    const int4* __restrict__ cnt4, int4* __restrict__ off4, int4* __restrict__ cur4)
{
    const int t = threadIdx.x;
    int4 v[16];
#pragma unroll
    for (int i = 0; i < 16; ++i) v[i] = cnt4[t * 16 + i];
    int sum = 0;
#pragma unroll
    for (int i = 0; i < 16; ++i) sum += v[i].x + v[i].y + v[i].z + v[i].w;

    const int lane = t & 63, w = t >> 6;
    int s = sum;
#pragma unroll
    for (int d = 1; d < 64; d <<= 1) {
        int u = __shfl_up(s, d, 64);
        if (lane >= d) s += u;
    }
    __shared__ int wsum[4];
    if (lane == 63) wsum[w] = s;
    __syncthreads();
    int base = 0;
    for (int i = 0; i < w; ++i) base += wsum[i];
    int run = base + s - sum;

#pragma unroll
    for (int i = 0; i < 16; ++i) {
        int4 o;
        o.x = run; run += v[i].x;
        o.y = run; run += v[i].y;
        o.z = run; run += v[i].z;
        o.w = run; run += v[i].w;
        off4[t * 16 + i] = o;
        cur4[t * 16 + i] = o;
    }
}

// ---------------- fallback: fill ----------------
__global__ __launch_bounds__(256) void fill_kernel(
    const int* __restrict__ bArr, const int* __restrict__ chArr,
    const int* __restrict__ zArr, const int* __restrict__ yArr,
    int* __restrict__ cursor, int* __restrict__ list, int N)
{
    int n = blockIdx.x * 256 + threadIdx.x;
    if (n >= N) return;
    int c = bArr[n] * 16 + chArr[n];
    int z0 = zArr[n] - PAD, y0 = yArr[n] - PAD;
    int tzlo = max(z0, 0) >> 3, tzhi = min(z0 + 20, 255) >> 3;
    int tylo = max(y0, 0) >> 3, tyhi = min(y0 + 20, 255) >> 3;
    for (int tz = tzlo; tz <= tzhi; ++tz)
        for (int ty = tylo; ty <= tyhi; ++ty) {
            int pos = atomicAdd(&cursor[c * 1024 + tz * 32 + ty], 1);
            list[pos] = n;
        }
}

// ---------------- gather: one block per (c, 8z, 8y, 64x) tile ----------------
template<bool F16>
__global__ __launch_bounds__(256) void gather_kernel(
    const float* __restrict__ psf_raw,
    const __half* __restrict__ pscaled,
    const int4* __restrict__ meta,
    const int* __restrict__ off, const int* __restrict__ cnt,
    const int* __restrict__ list,
    float* __restrict__ out,
    int cap)
{
    const int tile = blockIdx.x;
    const int ty = tile & 31;
    const int tz = (tile >> 5) & 31;
    const int c  = tile >> 10;
    const int t  = threadIdx.x;
    const int x    = t & 63;
    const int ysub = t >> 6;          // wave id 0..3
    const int zbase = tz * 8;
    const int ybase = ty * 8;

    float acc0[8] = {};
    float acc1[8] = {};

    int o, cn;
    if (cap > 0) { o = tile * cap; cn = min(cnt[tile], cap); }
    else         { o = off[tile];  cn = cnt[tile]; }

    int  nnext = (cn > 0) ? list[o] : 0;
    int4 mnext = (cn > 0) ? meta[nnext] : make_int4(0, 0, 0, 0);

    for (int i = 0; i < cn; ++i) {
        const int  n  = __builtin_amdgcn_readfirstlane(nnext);
        const int4 mt = mnext;
        const int  nj = list[o + min(i + 1, cn - 1)];  // prefetch list
        nnext = nj;
        mnext = meta[nj];                              // prefetch meta

        const int z0 = __builtin_amdgcn_readfirstlane(mt.x);
        const int y0 = __builtin_amdgcn_readfirstlane(mt.y);
        const int x0 = __builtin_amdgcn_readfirstlane(mt.z);
        const float sc = __int_as_float(__builtin_amdgcn_readfirstlane(mt.w));

        const int dx  = x - x0;
        const float wsc = ((unsigned)dx < 21u) ? (F16 ? 1.0f : sc) : 0.0f;
        const int dxc = min(max(dx, 0), 20);

        const int dy0 = ybase + ysub - y0;          // wave-uniform value
        const int dy1 = dy0 + 4;
        const int a0 = __any((unsigned)dy0 < 21u);  // wave-uniform scalar
        const int a1 = __any((unsigned)dy1 < 21u);
        const int row0 = dy0 * 21 + dxc;
        const int row1 = dy1 * 21 + dxc;

        const float*  pbf = psf_raw + (size_t)n * PSF3;
        const __half* pbh = pscaled + (size_t)n * PSF3P - ((4 - (n & 3)) & 3);

        if (a0 & a1) {
#pragma unroll
            for (int zi = 0; zi < 8; ++zi) {
                const int dz = zbase + zi - z0;
                const int zo = min(max(dz, 0), 20) * 441;
                const float w = ((unsigned)dz < 21u) ? wsc : 0.0f;
                float v0 = F16 ? __half2float(pbh[zo + row0]) : fmaxf(pbf[zo + row0], 0.0f);
                float v1 = F16 ? __half2float(pbh[zo + row1]) : fmaxf(pbf[zo + row1], 0.0f);
                acc0[zi] += w * v0;
                acc1[zi] += w * v1;
            }
        } else if (a0) {
#pragma unroll
            for (int zi = 0; zi < 8; ++zi) {
                const int dz = zbase + zi - z0;
                const int zo = min(max(dz, 0), 20) * 441;
                const float w = ((unsigned)dz < 21u) ? wsc : 0.0f;
                float v0 = F16 ? __half2float(pbh[zo + row0]) : fmaxf(pbf[zo + row0], 0.0f);
                acc0[zi] += w * v0;
            }
        } else if (a1) {
#pragma unroll
            for (int zi = 0; zi < 8; ++zi) {
                const int dz = zbase + zi - z0;
                const int zo = min(max(dz, 0), 20) * 441;
                const float w = ((unsigned)dz < 21u) ? wsc : 0.0f;
                float v1 = F16 ? __half2float(pbh[zo + row1]) : fmaxf(pbf[zo + row1], 0.0f);
                acc1[zi] += w * v1;
            }
        }
    }

    // coalesced nontemporal write-out
    const size_t outbase = (((size_t)c * 256 + zbase) * 256 + ybase) * 64 + x;
#pragma unroll
    for (int zi = 0; zi < 8; ++zi) {
        __builtin_nontemporal_store(acc0[zi],
            &out[outbase + (size_t)zi * (256 * 64) + (size_t)ysub * 64]);
        __builtin_nontemporal_store(acc1[zi],
            &out[outbase + (size_t)zi * (256 * 64) + (size_t)(ysub + 4) * 64]);
    }
}

extern "C" void kernel_launch(void* const* d_in, const int* in_sizes, int n_in,
                              void* d_out, int out_size, void* d_ws, size_t ws_size,
                              hipStream_t stream) {
    const float* psf_raw = (const float*)d_in[0];
    const float* i_val   = (const float*)d_in[1];
    const int*   bArr    = (const int*)d_in[2];
    const int*   chArr   = (const int*)d_in[3];
    const int*   zArr    = (const int*)d_in[4];
    const int*   yArr    = (const int*)d_in[5];
    const int*   xArr    = (const int*)d_in[6];
    float* out = (float*)d_out;

    const int N = in_sizes[1];   // 8192 points

    char* ws = (char*)d_ws;
    int4*   meta    = (int4*)(ws + META_OFF);
    int*    cnt     = (int*)(ws + CNT_OFF);
    int*    offp    = (int*)(ws + SCAN_OFF);
    int*    cursor  = (int*)(ws + CUR_OFF);
    int*    list    = (int*)(ws + LIST_OFF);
    __half* pscaled = (__half*)(ws + PSC_OFF) + 16;   // 32B front slack

    // path selection by available workspace
    const size_t psc_need = (size_t)PSC_OFF + 64 + (size_t)N * PSF3P * 2;
    bool f16 = (ws_size >= psc_need);
    int cap;
    if (ws_size >= (size_t)LIST_OFF + (size_t)CAP * NTILES * 4) {
        cap = CAP;
    } else {
        size_t avail = (ws_size > LIST_OFF) ? ws_size - LIST_OFF : 0;
        size_t cap_s = avail / ((size_t)NTILES * sizeof(int));
        cap = (cap_s >= 24) ? (int)((cap_s < 64) ? cap_s : 64) : 0;
    }
    if (cap == 0) f16 = false;

    (void)hipMemsetAsync(cnt, 0, NTILES * sizeof(int), stream);

    if (f16)
        psf_scale_fill_kernel<true><<<N, 256, 0, stream>>>(psf_raw, i_val, bArr, chArr,
            zArr, yArr, xArr, meta, cnt, list, cap, pscaled);
    else
        psf_scale_fill_kernel<false><<<N, 256, 0, stream>>>(psf_raw, i_val, bArr, chArr,
            zArr, yArr, xArr, meta, cnt, list, cap, pscaled);

    if (cap == 0) {
        scan_kernel<<<1, 256, 0, stream>>>((const int4*)cnt, (int4*)offp, (int4*)cursor);
        fill_kernel<<<(N + 255) / 256, 256, 0, stream>>>(bArr, chArr, zArr, yArr,
                                                         cursor, list, N);
    }

    if (f16)
        gather_kernel<true><<<NTILES, 256, 0, stream>>>(psf_raw, pscaled, meta,
            offp, cnt, list, out, cap);
    else
        gather_kernel<false><<<NTILES, 256, 0, stream>>>(psf_raw, pscaled, meta,
            offp, cnt, list, out, cap);
}